// Round 1
// baseline (309.797 us; speedup 1.0000x reference)
//
#include <hip/hip_runtime.h>
#include <hip/hip_bf16.h>
#include <cstdint>

#define S_LEN 4096
#define NHEAD 4
#define HDIM 32
#define HID 128
#define CBATCH 4
#define EPSW 1e-8f

typedef __attribute__((ext_vector_type(8))) short short8v;
typedef __attribute__((ext_vector_type(4))) float float4v;

__device__ __forceinline__ unsigned short f2bf(float f) {
    unsigned int u = __float_as_uint(f);
    return (unsigned short)((u + 0x7fffu + ((u >> 16) & 1u)) >> 16);
}

// ---------------------------------------------------------------------------
// Kernel 1: fused QKV projection.  out = (x @ W.T + b) [*SCALE for Q]
// x: (C*S, 128) fp32.  Writes Q/K/V as bf16 in (C, NH, S, HD) layout.
// Block: 256 thr, computes 64 rows x 64 cols.  grid=(256 row-tiles, 2, 3)
// ---------------------------------------------------------------------------
__global__ __launch_bounds__(256) void qkv_proj_kernel(
    const float* __restrict__ x,
    const float* __restrict__ Wq, const float* __restrict__ bq,
    const float* __restrict__ Wk, const float* __restrict__ bk,
    const float* __restrict__ Wv, const float* __restrict__ bv,
    unsigned short* __restrict__ Qo, unsigned short* __restrict__ Ko,
    unsigned short* __restrict__ Vo)
{
    __shared__ float xs[64][132];   // pad: rows 8 apart share bank (2-way, free)
    __shared__ float wsT[64][68];   // [k][n] transposed W tile for one K-phase

    const int tid = threadIdx.x;
    const int mrow0 = blockIdx.x * 64;
    const int n0 = blockIdx.y * 64;
    const int p = blockIdx.z;
    const float* W    = (p == 0) ? Wq : (p == 1) ? Wk : Wv;
    const float* bias = (p == 0) ? bq : (p == 1) ? bk : bv;
    unsigned short* Out = (p == 0) ? Qo : (p == 1) ? Ko : Vo;

    // stage x tile 64x128
    for (int i = tid; i < 64 * 32; i += 256) {
        int r = i >> 5, c4 = (i & 31) * 4;
        *(float4*)&xs[r][c4] = *(const float4*)&x[(size_t)(mrow0 + r) * HID + c4];
    }

    float acc[4][4] = {};
    const int tr = tid >> 4;   // 0..15 -> rows tr*4..tr*4+3
    const int tc = tid & 15;   // cols tc*4..tc*4+3

    for (int ph = 0; ph < 2; ++ph) {
        __syncthreads();
        // stage W tile transposed: wsT[k][n] = W[n0+n][ph*64+k]
        for (int i = tid; i < 64 * 16; i += 256) {
            int r = i >> 4, c4 = (i & 15) * 4;
            float4 wv = *(const float4*)&W[(size_t)(n0 + r) * HID + ph * 64 + c4];
            wsT[c4 + 0][r] = wv.x;
            wsT[c4 + 1][r] = wv.y;
            wsT[c4 + 2][r] = wv.z;
            wsT[c4 + 3][r] = wv.w;
        }
        __syncthreads();
        #pragma unroll 4
        for (int k4 = 0; k4 < 16; ++k4) {
            float4 xv[4];
            #pragma unroll
            for (int i = 0; i < 4; ++i)
                xv[i] = *(const float4*)&xs[tr * 4 + i][ph * 64 + k4 * 4];
            #pragma unroll
            for (int kk = 0; kk < 4; ++kk) {
                float4 wv = *(const float4*)&wsT[k4 * 4 + kk][tc * 4];
                #pragma unroll
                for (int i = 0; i < 4; ++i) {
                    float xk = ((const float*)&xv[i])[kk];
                    acc[i][0] += xk * wv.x;
                    acc[i][1] += xk * wv.y;
                    acc[i][2] += xk * wv.z;
                    acc[i][3] += xk * wv.w;
                }
            }
        }
    }

    const float scale = (p == 0) ? 0.17677669529663687f : 1.0f; // 32^-0.5 folded into Q
    float4 bv4 = *(const float4*)&bias[n0 + tc * 4];
    const int nbase = n0 + tc * 4;
    const int h = nbase >> 5;
    const int d = nbase & 31;
    #pragma unroll
    for (int i = 0; i < 4; ++i) {
        int m = mrow0 + tr * 4 + i;
        int c = m >> 12, s = m & 4095;
        unsigned short pk[4];
        pk[0] = f2bf((acc[i][0] + bv4.x) * scale);
        pk[1] = f2bf((acc[i][1] + bv4.y) * scale);
        pk[2] = f2bf((acc[i][2] + bv4.z) * scale);
        pk[3] = f2bf((acc[i][3] + bv4.w) * scale);
        *(uint2*)&Out[((size_t)(c * NHEAD + h) * S_LEN + s) * HDIM + d] = *(uint2*)pk;
    }
}

// ---------------------------------------------------------------------------
// Kernel 2: transpose V (C,NH,S,HD) -> Vt (C,NH,HD,S), bf16.
// Block 256 thr handles one (c,h) x 64-s chunk.
// ---------------------------------------------------------------------------
__global__ __launch_bounds__(256) void vtrans_kernel(
    const unsigned short* __restrict__ V, unsigned short* __restrict__ Vt)
{
    __shared__ unsigned short vs[64][40];
    const int tid = threadIdx.x;
    const int chh = blockIdx.y;          // c*NH + h
    const int s0 = blockIdx.x * 64;
    const size_t base = (size_t)chh * S_LEN * HDIM;
    {
        int r = tid >> 2, ch = (tid & 3) * 8;
        *(uint4*)&vs[r][ch] = *(const uint4*)&V[base + (size_t)(s0 + r) * HDIM + ch];
    }
    __syncthreads();
    {
        int dd = tid >> 3, chs = (tid & 7) * 8;
        unsigned short pk[8];
        #pragma unroll
        for (int j = 0; j < 8; ++j) pk[j] = vs[chs + j][dd];
        *(uint4*)&Vt[(size_t)chh * HDIM * S_LEN + (size_t)dd * S_LEN + s0 + chs] = *(uint4*)pk;
    }
}

// ---------------------------------------------------------------------------
// Kernel 3: attention.  One block = (c, 32-query tile); wave w = head w.
// softmax(qk*scale + log(max(ew,eps))) == max(ew,eps)*exp(qk*scale)/sum
// -> no max tracking needed (|qk*scale| <= ~8, exp safe in fp32).
// Swapped QK mfma: lane holds scores for query=lane&15, keys=4g+r.
// ---------------------------------------------------------------------------
__global__ __launch_bounds__(256) void attn_kernel(
    const unsigned short* __restrict__ Q, const unsigned short* __restrict__ K,
    const unsigned short* __restrict__ Vt, const float* __restrict__ ew,
    float* __restrict__ attnout)
{
    const int tid = threadIdx.x;
    const int w = tid >> 6;          // head
    const int lane = tid & 63;
    const int li = lane & 15;
    const int g = lane >> 4;
    const int c = blockIdx.y;
    const int qbase = blockIdx.x * 32;

    const size_t hb = (size_t)(c * NHEAD + w) * S_LEN * HDIM;
    const unsigned short* Qh = Q + hb;
    const unsigned short* Kh = K + hb;
    const unsigned short* Vth = Vt + hb;
    const float* ewc = ew + (size_t)c * S_LEN * S_LEN;

    short8v qf[2];
    #pragma unroll
    for (int qs = 0; qs < 2; ++qs)
        qf[qs] = *(const short8v*)&Qh[(size_t)(qbase + qs * 16 + li) * HDIM + g * 8];

    float4v oacc[2][2] = {};
    float denom[2] = {0.f, 0.f};
    const float4v zero4 = {0.f, 0.f, 0.f, 0.f};

    for (int kb = 0; kb < S_LEN; kb += 32) {
        short8v kf[2];
        kf[0] = *(const short8v*)&Kh[(size_t)(kb + li) * HDIM + g * 8];
        kf[1] = *(const short8v*)&Kh[(size_t)(kb + 16 + li) * HDIM + g * 8];

        short8v vf[2];
        #pragma unroll
        for (int db = 0; db < 2; ++db) {
            const unsigned short* vp = &Vth[(size_t)(db * 16 + li) * S_LEN + kb + g * 4];
            union { short8v v; uint2 u2[2]; } vu;
            vu.u2[0] = *(const uint2*)vp;
            vu.u2[1] = *(const uint2*)(vp + 16);
            vf[db] = vu.v;
        }

        #pragma unroll
        for (int qs = 0; qs < 2; ++qs) {
            float4v s0 = __builtin_amdgcn_mfma_f32_16x16x32_bf16(kf[0], qf[qs], zero4, 0, 0, 0);
            float4v s1 = __builtin_amdgcn_mfma_f32_16x16x32_bf16(kf[1], qf[qs], zero4, 0, 0, 0);
            const float* ewrow = &ewc[(size_t)(qbase + qs * 16 + li) * S_LEN + kb];
            float4 e0 = *(const float4*)&ewrow[g * 4];
            float4 e1 = *(const float4*)&ewrow[16 + g * 4];
            float p[8];
            p[0] = fmaxf(e0.x, EPSW) * __expf(s0[0]);
            p[1] = fmaxf(e0.y, EPSW) * __expf(s0[1]);
            p[2] = fmaxf(e0.z, EPSW) * __expf(s0[2]);
            p[3] = fmaxf(e0.w, EPSW) * __expf(s0[3]);
            p[4] = fmaxf(e1.x, EPSW) * __expf(s1[0]);
            p[5] = fmaxf(e1.y, EPSW) * __expf(s1[1]);
            p[6] = fmaxf(e1.z, EPSW) * __expf(s1[2]);
            p[7] = fmaxf(e1.w, EPSW) * __expf(s1[3]);
            denom[qs] += ((p[0] + p[1]) + (p[2] + p[3])) + ((p[4] + p[5]) + (p[6] + p[7]));
            union { short8v v; unsigned short us[8]; } pu;
            #pragma unroll
            for (int j = 0; j < 8; ++j) pu.us[j] = f2bf(p[j]);
            #pragma unroll
            for (int db = 0; db < 2; ++db)
                oacc[qs][db] = __builtin_amdgcn_mfma_f32_16x16x32_bf16(vf[db], pu.v, oacc[qs][db], 0, 0, 0);
        }
    }

    #pragma unroll
    for (int qs = 0; qs < 2; ++qs) {
        float t = denom[qs];
        t += __shfl_xor(t, 16, 64);
        t += __shfl_xor(t, 32, 64);
        float inv = 1.0f / t;
        const int q = qbase + qs * 16 + li;
        #pragma unroll
        for (int db = 0; db < 2; ++db) {
            float4 o;
            o.x = oacc[qs][db][0] * inv;
            o.y = oacc[qs][db][1] * inv;
            o.z = oacc[qs][db][2] * inv;
            o.w = oacc[qs][db][3] * inv;
            *(float4*)&attnout[((size_t)(c * S_LEN) + q) * HID + w * HDIM + db * 16 + g * 4] = o;
        }
    }
}

// ---------------------------------------------------------------------------
// Kernel 4: output projection. out = attnout @ Wo.T + bo   (all fp32)
// ---------------------------------------------------------------------------
__global__ __launch_bounds__(256) void out_proj_kernel(
    const float* __restrict__ ain, const float* __restrict__ Wo,
    const float* __restrict__ bo, float* __restrict__ out)
{
    __shared__ float xs[64][132];
    __shared__ float wsT[64][68];

    const int tid = threadIdx.x;
    const int mrow0 = blockIdx.x * 64;
    const int n0 = blockIdx.y * 64;

    for (int i = tid; i < 64 * 32; i += 256) {
        int r = i >> 5, c4 = (i & 31) * 4;
        *(float4*)&xs[r][c4] = *(const float4*)&ain[(size_t)(mrow0 + r) * HID + c4];
    }

    float acc[4][4] = {};
    const int tr = tid >> 4;
    const int tc = tid & 15;

    for (int ph = 0; ph < 2; ++ph) {
        __syncthreads();
        for (int i = tid; i < 64 * 16; i += 256) {
            int r = i >> 4, c4 = (i & 15) * 4;
            float4 wv = *(const float4*)&Wo[(size_t)(n0 + r) * HID + ph * 64 + c4];
            wsT[c4 + 0][r] = wv.x;
            wsT[c4 + 1][r] = wv.y;
            wsT[c4 + 2][r] = wv.z;
            wsT[c4 + 3][r] = wv.w;
        }
        __syncthreads();
        #pragma unroll 4
        for (int k4 = 0; k4 < 16; ++k4) {
            float4 xv[4];
            #pragma unroll
            for (int i = 0; i < 4; ++i)
                xv[i] = *(const float4*)&xs[tr * 4 + i][ph * 64 + k4 * 4];
            #pragma unroll
            for (int kk = 0; kk < 4; ++kk) {
                float4 wv = *(const float4*)&wsT[k4 * 4 + kk][tc * 4];
                #pragma unroll
                for (int i = 0; i < 4; ++i) {
                    float xk = ((const float*)&xv[i])[kk];
                    acc[i][0] += xk * wv.x;
                    acc[i][1] += xk * wv.y;
                    acc[i][2] += xk * wv.z;
                    acc[i][3] += xk * wv.w;
                }
            }
        }
    }

    float4 bv4 = *(const float4*)&bo[n0 + tc * 4];
    #pragma unroll
    for (int i = 0; i < 4; ++i) {
        int m = mrow0 + tr * 4 + i;
        float4 o;
        o.x = acc[i][0] + bv4.x;
        o.y = acc[i][1] + bv4.y;
        o.z = acc[i][2] + bv4.z;
        o.w = acc[i][3] + bv4.w;
        *(float4*)&out[(size_t)m * HID + n0 + tc * 4] = o;
    }
}

extern "C" void kernel_launch(void* const* d_in, const int* in_sizes, int n_in,
                              void* d_out, int out_size, void* d_ws, size_t ws_size,
                              hipStream_t stream) {
    const float* x  = (const float*)d_in[0];
    const float* ew = (const float*)d_in[1];
    const float* Wq = (const float*)d_in[2];
    const float* bq = (const float*)d_in[3];
    const float* Wk = (const float*)d_in[4];
    const float* bk = (const float*)d_in[5];
    const float* Wv = (const float*)d_in[6];
    const float* bv = (const float*)d_in[7];
    const float* Wo = (const float*)d_in[8];
    const float* bo = (const float*)d_in[9];
    float* out = (float*)d_out;

    char* ws = (char*)d_ws;
    const size_t QSZ = (size_t)CBATCH * NHEAD * S_LEN * HDIM * sizeof(unsigned short); // 4 MiB
    unsigned short* Qw  = (unsigned short*)(ws);
    unsigned short* Kw  = (unsigned short*)(ws + QSZ);
    unsigned short* Vw  = (unsigned short*)(ws + 2 * QSZ);
    unsigned short* Vtw = (unsigned short*)(ws + 3 * QSZ);
    float* attn = (float*)(ws + 4 * QSZ);   // (C,S,128) fp32, 8 MiB

    qkv_proj_kernel<<<dim3(256, 2, 3), 256, 0, stream>>>(x, Wq, bq, Wk, bk, Wv, bv, Qw, Kw, Vw);
    vtrans_kernel<<<dim3(S_LEN / 64, CBATCH * NHEAD), 256, 0, stream>>>(Vw, Vtw);
    attn_kernel<<<dim3(S_LEN / 32, CBATCH), 256, 0, stream>>>(Qw, Kw, Vtw, ew, attn);
    out_proj_kernel<<<dim3(256, 2), 256, 0, stream>>>(attn, Wo, bo, out);
}